// Round 4
// baseline (626.517 us; speedup 1.0000x reference)
//
#include <hip/hip_runtime.h>

using u16 = unsigned short;
using f32x4 = __attribute__((ext_vector_type(4))) float;
using short8 = __attribute__((ext_vector_type(8))) short;

__device__ __forceinline__ float bf2f(u16 u) {
    union { unsigned int i; float f; } v; v.i = ((unsigned int)u) << 16; return v.f;
}
__device__ __forceinline__ u16 f2bf(float f) {
    union { float f; unsigned int i; } v; v.f = f;
    unsigned int u = v.i;
    u += 0x7fffu + ((u >> 16) & 1u);
    return (u16)(u >> 16);
}
__device__ __forceinline__ void gload16(const u16* g, u16* l) {
    __builtin_amdgcn_global_load_lds((const __attribute__((address_space(1))) void*)g,
                                     (__attribute__((address_space(3))) void*)l, 16, 0, 0);
}
#define WAITV(n) asm volatile("s_waitcnt vmcnt(" #n ")" ::: "memory")
#define WAITLGKM() asm volatile("s_waitcnt lgkmcnt(0)" ::: "memory")
__device__ __forceinline__ void barrier_() {
    asm volatile("" ::: "memory");
    __builtin_amdgcn_s_barrier();
    asm volatile("" ::: "memory");
}

// ---------------- prep: weight transposes/permutations to bf16 ----------------
__global__ __launch_bounds__(256) void prep_weights(
    const float* __restrict__ Wq, const float* __restrict__ Wkv,
    const float* __restrict__ Wo, const float* __restrict__ Win,
    const float* __restrict__ Wout, const float* __restrict__ cg,
    u16* __restrict__ wqkvt, u16* __restrict__ wot,
    u16* __restrict__ winp, u16* __restrict__ woutt)
{
    int i = blockIdx.x * 256 + threadIdx.x;
    if (i < 1536 * 512) {
        int n = i >> 9, c = i & 511;
        float v = (n < 512) ? Wq[c * 512 + n] : Wkv[c * 1024 + (n - 512)];
        wqkvt[i] = f2bf(v); return;
    }
    i -= 1536 * 512;
    if (i < 512 * 512) {
        int cc = i >> 9, k = i & 511;
        wot[i] = f2bf(Wo[k * 512 + cc]); return;
    }
    i -= 512 * 512;
    if (i < 2816 * 512) {
        int n = i >> 9, c = i & 511;
        int jj = ((n >> 5) << 4) + (n & 15);
        int gate = (n >> 4) & 1;
        float v = (jj < 1365) ? Win[c * 2730 + jj + gate * 1365] : 0.f;
        winp[i] = f2bf(v); return;
    }
    i -= 2816 * 512;
    if (i < 512 * 1408) {
        int cc = i / 1408, j = i % 1408;
        float v = (j < 1365) ? Wout[j * 512 + cc] * cg[j] : 0.f;
        woutt[i] = f2bf(v); return;
    }
}

__global__ __launch_bounds__(256) void ssum_kernel(
    const float* __restrict__ Wout, const float* __restrict__ cg, float* __restrict__ ssum)
{
    int c = blockIdx.x * 256 + threadIdx.x;
    if (c >= 512) return;
    float s = 0.f;
    for (int j = 0; j < 1365; ++j) s += Wout[j * 512 + c] * cg[j];
    ssum[c] = s;
}

// ---------------- CPB relative-position bias MLP: bias[8][16][16] ----------------
__global__ __launch_bounds__(256) void bias_kernel(
    const float* __restrict__ w1, const float* __restrict__ b1,
    const float* __restrict__ w2, const float* __restrict__ b2,
    const float* __restrict__ w3, const float* __restrict__ b3,
    float* __restrict__ bias)
{
    __shared__ float h1[256], h2[256];
    int rc = blockIdx.x;
    int ti = rc >> 4, tj = rc & 15;
    int j = threadIdx.x;
    float r = (float)(ti - tj);
    float rl = (r > 0.f) ? logf(r + 1.f) : ((r < 0.f) ? -logf(1.f - r) : 0.f);
    float a = rl * w1[j] + b1[j];
    h1[j] = a / (1.f + __expf(-a));
    __syncthreads();
    float acc = b2[j];
    for (int k = 0; k < 256; ++k) acc += h1[k] * w2[k * 256 + j];
    h2[j] = acc / (1.f + __expf(-acc));
    __syncthreads();
    if (j < 8) {
        float ab = b3[j];
        for (int k = 0; k < 256; ++k) ab += h2[k] * w3[k * 8 + j];
        bias[j * 256 + ti * 16 + tj] = ab;
    }
}

// ---------------- K1: temporal LayerNorm, write xn & xt token-major bf16 ----------------
__global__ __launch_bounds__(256) void k1_norm(
    const float* __restrict__ x, const int* __restrict__ frp,
    const float* __restrict__ g_norm, const float* __restrict__ pos_emb,
    const float* __restrict__ fr_emb,
    u16* __restrict__ xn, u16* __restrict__ xt)
{
    __shared__ u16 tile[256 * 34];
    const int bid = blockIdx.x;
    const int b = bid >> 10, rem = bid & 1023;
    const int hw0 = (rem >> 4) << 4;
    const int c0 = (rem & 15) << 5;
    const int tid = threadIdx.x;
    const int hwl = tid & 15, cl = tid >> 4;
    const int fr = frp[0] - 1;
    float v[2][16], mean2[2], ri2[2], gg2[2], fv2[2];
    for (int cp = 0; cp < 2; ++cp) {
        const int c = c0 + cl + (cp << 4);
        const float* xp = x + (size_t)(b * 512 + c) * 16384 + hw0 + hwl;
        const float fv = fr_emb[fr * 512 + c];
        float s1 = 0.f, s2 = 0.f;
#pragma unroll
        for (int t = 0; t < 16; ++t) {
            float xv = xp[t * 1024];
            v[cp][t] = xv;
            float xe = xv + pos_emb[t * 512 + c] + fv;
            s1 += xe; s2 += xe * xe;
        }
        float m = s1 * 0.0625f;
        float var = s2 * 0.0625f - m * m;
        mean2[cp] = m; ri2[cp] = rsqrtf(fmaxf(var, 1e-5f));
        gg2[cp] = g_norm[c]; fv2[cp] = fv;
    }
    for (int cp = 0; cp < 2; ++cp) {
        const int c = c0 + cl + (cp << 4);
#pragma unroll
        for (int t = 0; t < 16; ++t) {
            float xe = v[cp][t] + pos_emb[t * 512 + c] + fv2[cp];
            tile[((t << 4) + hwl) * 34 + cl + (cp << 4)] = f2bf((xe - mean2[cp]) * ri2[cp] * gg2[cp]);
        }
    }
    __syncthreads();
    for (int it = 0; it < 32; ++it) {
        int rowl = (tid >> 5) + (it << 3);
        int col = tid & 31;
        size_t p = (size_t)b * 16384 + (size_t)(rowl >> 4) * 1024 + hw0 + (rowl & 15);
        xn[p * 512 + c0 + col] = tile[rowl * 34 + col];
    }
    __syncthreads();
    for (int cp = 0; cp < 2; ++cp)
#pragma unroll
        for (int t = 0; t < 16; ++t)
            tile[((t << 4) + hwl) * 34 + cl + (cp << 4)] = f2bf(v[cp][t]);
    __syncthreads();
    for (int it = 0; it < 32; ++it) {
        int rowl = (tid >> 5) + (it << 3);
        int col = tid & 31;
        size_t p = (size_t)b * 16384 + (size_t)(rowl >> 4) * 1024 + hw0 + (rowl & 15);
        xt[p * 512 + c0 + col] = tile[rowl * 34 + col];
    }
}

// ============ 8-wave 256x256 phase-split GEMM (faithful m201-style schedule) ============
// Waves 2(M)x4(N), per-wave 128x64 output. BK=64 double-buffered (128 KiB LDS).
// Per K-tile: start {issue 2 next-tile rounds; vmcnt(2); barrier} then 4 phases, each
// {ds_reads + 2 staging rounds; barrier; lgkmcnt(0); setprio(1) 16 MFMA setprio(0); barrier}.
// vmcnt counted (2 loads always in flight, never 0 mid-loop — T4). XCD-chunked swizzle (T1).
template<int EPI>
__global__ __launch_bounds__(512, 2) void gemm8(
    const u16* __restrict__ A, const u16* __restrict__ B, int K, int Nb,
    u16* __restrict__ outb, float* __restrict__ outf,
    const u16* __restrict__ addb,
    const float* __restrict__ marr, const float* __restrict__ rinv,
    const float* __restrict__ ssum, int ldOut)
{
    __shared__ u16 lds[65536];   // 2 bufs x (A 256x64 + B 256x64)
    const int tid = threadIdx.x, lane = tid & 63, w = tid >> 6;
    const int wr = w >> 2, wc = w & 3;
    const int wr128 = wr * 128, wc64 = wc * 64;
    const int l15 = lane & 15, l16 = lane >> 4;
    const int w8 = w * 8;
    const int cpx = gridDim.x >> 3;
    const int wgid = (blockIdx.x & 7) * cpx + (blockIdx.x >> 3);
    const int p0 = (wgid / Nb) * 256, n0 = (wgid % Nb) * 256;
    const u16* Ag = A + (size_t)p0 * K;
    const u16* Bg = B + (size_t)n0 * K;

    auto stageA = [&](u16* sA, int kt, int rb) {
        int r = rb + w8 + (lane >> 3);
        int cg = (lane & 7) ^ (r & 7);
        gload16(Ag + (size_t)r * K + kt + cg * 8, sA + (rb + w8) * 64);
    };
    auto stageB = [&](u16* sB, int kt, int rb) {
        int r = rb + w8 + (lane >> 3);
        int cg = (lane & 7) ^ (r & 7);
        gload16(Bg + (size_t)r * K + kt + cg * 8, sB + (rb + w8) * 64);
    };
    auto rdA = [&](const u16* lA, int m, int kk) -> short8 {
        int r = wr128 + m * 16 + l15;
        int cc = ((kk << 2) + l16) ^ (r & 7);
        return *(const short8*)(lA + r * 64 + cc * 8);
    };
    auto rdB = [&](const u16* lB, int n, int kk) -> short8 {
        int r = wc64 + n * 16 + l15;
        int cc = ((kk << 2) + l16) ^ (r & 7);
        return *(const short8*)(lB + r * 64 + cc * 8);
    };

    f32x4 acc[8][4] = {};
    {   // prologue: stage all 8 rounds of K-tile 0 into buf0
        u16* sA = lds; u16* sB = lds + 16384;
        stageA(sA, 0, 0);  stageA(sA, 0, 64); stageA(sA, 0, 128); stageA(sA, 0, 192);
        stageB(sB, 0, 0);  stageB(sB, 0, 64); stageB(sB, 0, 128); stageB(sB, 0, 192);
    }
    const int NT = K >> 6;
    for (int t = 0; t < NT; ++t) {
        const u16* lA = lds + (t & 1) * 32768;
        const u16* lB = lA + 16384;
        u16* sA = lds + ((t & 1) ^ 1) * 32768;
        u16* sB = sA + 16384;
        const int kt = (t + 1) << 6;
        const bool pf = (t + 1 < NT);
        short8 a_[4][2], b_[2][2], b2_[2][2];
        // ---- K-tile start: issue 2 next-tile rounds BEFORE the counted wait
        if (pf) {
            stageA(sA, kt, 0); stageA(sA, kt, 64);
            WAITV(2);              // completes all 8 rounds of tile t (oldest); 2 in flight
        } else {
            WAITV(0);
        }
        barrier_();
        // ---- P0: quadrant (m0-3 x n0-1)
#pragma unroll
        for (int m = 0; m < 4; ++m) { a_[m][0] = rdA(lA, m, 0); a_[m][1] = rdA(lA, m, 1); }
#pragma unroll
        for (int n = 0; n < 2; ++n) { b_[n][0] = rdB(lB, n, 0); b_[n][1] = rdB(lB, n, 1); }
        if (pf) { stageA(sA, kt, 128); stageA(sA, kt, 192); }
        barrier_();
        WAITLGKM();
        __builtin_amdgcn_s_setprio(1);
#pragma unroll
        for (int kk = 0; kk < 2; ++kk)
#pragma unroll
            for (int m = 0; m < 4; ++m)
#pragma unroll
                for (int n = 0; n < 2; ++n)
                    acc[m][n] = __builtin_amdgcn_mfma_f32_16x16x32_bf16(a_[m][kk], b_[n][kk], acc[m][n], 0, 0, 0);
        __builtin_amdgcn_s_setprio(0);
        barrier_();
        // ---- P1: quadrant (m0-3 x n2-3)
#pragma unroll
        for (int n = 0; n < 2; ++n) { b2_[n][0] = rdB(lB, n + 2, 0); b2_[n][1] = rdB(lB, n + 2, 1); }
        if (pf) { stageB(sB, kt, 0); stageB(sB, kt, 64); }
        barrier_();
        WAITLGKM();
        __builtin_amdgcn_s_setprio(1);
#pragma unroll
        for (int kk = 0; kk < 2; ++kk)
#pragma unroll
            for (int m = 0; m < 4; ++m)
#pragma unroll
                for (int n = 0; n < 2; ++n)
                    acc[m][n + 2] = __builtin_amdgcn_mfma_f32_16x16x32_bf16(a_[m][kk], b2_[n][kk], acc[m][n + 2], 0, 0, 0);
        __builtin_amdgcn_s_setprio(0);
        barrier_();
        // ---- P2: quadrant (m4-7 x n2-3)
#pragma unroll
        for (int m = 0; m < 4; ++m) { a_[m][0] = rdA(lA, m + 4, 0); a_[m][1] = rdA(lA, m + 4, 1); }
        if (pf) { stageB(sB, kt, 128); stageB(sB, kt, 192); }
        barrier_();
        WAITLGKM();
        __builtin_amdgcn_s_setprio(1);
#pragma unroll
        for (int kk = 0; kk < 2; ++kk)
#pragma unroll
            for (int m = 0; m < 4; ++m)
#pragma unroll
                for (int n = 0; n < 2; ++n)
                    acc[m + 4][n + 2] = __builtin_amdgcn_mfma_f32_16x16x32_bf16(a_[m][kk], b2_[n][kk], acc[m + 4][n + 2], 0, 0, 0);
        __builtin_amdgcn_s_setprio(0);
        barrier_();
        // ---- P3: quadrant (m4-7 x n0-1)
#pragma unroll
        for (int n = 0; n < 2; ++n) { b_[n][0] = rdB(lB, n, 0); b_[n][1] = rdB(lB, n, 1); }
        barrier_();
        WAITLGKM();
        __builtin_amdgcn_s_setprio(1);
#pragma unroll
        for (int kk = 0; kk < 2; ++kk)
#pragma unroll
            for (int m = 0; m < 4; ++m)
#pragma unroll
                for (int n = 0; n < 2; ++n)
                    acc[m + 4][n] = __builtin_amdgcn_mfma_f32_16x16x32_bf16(a_[m][kk], b_[n][kk], acc[m + 4][n], 0, 0, 0);
        __builtin_amdgcn_s_setprio(0);
        barrier_();
    }

    if constexpr (EPI == 0 || EPI == 1) {
#pragma unroll
        for (int m = 0; m < 8; ++m)
#pragma unroll
            for (int n = 0; n < 4; ++n) {
                int row = p0 + wr128 + m * 16 + (l16 << 2);
                int col = n0 + wc64 + n * 16 + l15;
#pragma unroll
                for (int r = 0; r < 4; ++r) {
                    float vv = acc[m][n][r];
                    if constexpr (EPI == 1) vv += bf2f(addb[(size_t)(row + r) * ldOut + col]);
                    outb[(size_t)(row + r) * ldOut + col] = f2bf(vv);
                }
            }
    } else if constexpr (EPI == 2) {
#pragma unroll
        for (int m = 0; m < 8; ++m)
#pragma unroll
            for (int np = 0; np < 2; ++np) {
                int nv = np << 1;
                int colBase = n0 + wc64 + nv * 16 + l15;
                int jj = ((colBase >> 5) << 4) + (colBase & 15);
                int rowb = p0 + wr128 + m * 16 + (l16 << 2);
                int t = (rowb >> 10) & 15;
#pragma unroll
                for (int r = 0; r < 4; ++r) {
                    int p = rowb + r;
                    float vv = acc[m][nv][r], gv = acc[m][nv + 1][r];
                    float glu = vv * 0.5f * gv * (1.f + erff(gv * 0.70710678f));
                    if (jj >= 1365) {
                        outb[(size_t)p * 1408 + jj] = 0;
                    } else if (jj >= 683) {
                        if (t < 15) outb[(size_t)(p + 1024) * 1408 + jj] = f2bf(glu);
                        if (t == 0) outb[(size_t)p * 1408 + jj] = 0;
                    } else {
                        outb[(size_t)p * 1408 + jj] = f2bf(glu);
                    }
                }
            }
    } else {
        // EPI 3: channel-LN apply + residual + transposed fp32 store to native layout
        float* ldsT = (float*)lds;
        const int bb = p0 >> 14, tt = (p0 >> 10) & 15, hw0 = p0 & 1023;
        __syncthreads();
        for (int ch = 0; ch < 8; ++ch) {
            if (ch) __syncthreads();
            if (wc == (ch >> 1)) {
#pragma unroll
                for (int nn = 0; nn < 2; ++nn) {
                    int n = ((ch & 1) << 1) + nn;
                    int col = n0 + wc64 + n * 16 + l15;
                    int cl = (nn << 4) + l15;
                    float ssv = ssum[col];
#pragma unroll
                    for (int m = 0; m < 8; ++m) {
                        int rl = wr128 + m * 16 + (l16 << 2);
#pragma unroll
                        for (int r = 0; r < 4; ++r) {
                            int p = p0 + rl + r;
                            float vv = rinv[p] * (acc[m][n][r] - marr[p] * ssv)
                                     + bf2f(addb[(size_t)p * 512 + col]);
                            ldsT[cl * 260 + rl + r] = vv;
                        }
                    }
                }
            }
            __syncthreads();
#pragma unroll
            for (int e = 0; e < 16; ++e) {
                int li = e * 512 + tid;
                int cl = li >> 8, rr = li & 255;
                int c = n0 + ch * 32 + cl;
                outf[((size_t)(bb * 512 + c) * 16 + tt) * 1024 + hw0 + rr] = ldsT[cl * 260 + rr];
            }
        }
    }
}

// ---------------- 2-barrier 128x128 GEMM (proven R3 structure; EPI1 control) ----------------
template<int EPI>
__global__ __launch_bounds__(256, 2) void gemm_bt(
    const u16* __restrict__ A, const u16* __restrict__ B, int K, int Nb,
    u16* __restrict__ outb, float* __restrict__ outf,
    const u16* __restrict__ addb,
    const float* __restrict__ marr, const float* __restrict__ rinv,
    const float* __restrict__ ssum, int ldOut)
{
    __shared__ u16 lds[2 * 128 * 64];
    u16* lA = lds;
    u16* lB = lds + 128 * 64;
    const int tid = threadIdx.x, lane = tid & 63, w = tid >> 6;
    const int wr = w >> 1, wc = w & 1;
    const int cpx = gridDim.x >> 3;
    const int wgid = (blockIdx.x & 7) * cpx + (blockIdx.x >> 3);
    const int p0 = (wgid / Nb) * 128, n0 = (wgid % Nb) * 128;
    f32x4 acc[4][4] = {};
    for (int kt = 0; kt < K; kt += 64) {
        for (int i = 0; i < 4; ++i) {
            int rb = w * 4 + i;
            int r = rb * 8 + (lane >> 3);
            int cg = (lane & 7) ^ (r & 7);
            gload16(A + (size_t)(p0 + r) * K + (kt + cg * 8), lA + rb * 512);
            gload16(B + (size_t)(n0 + r) * K + (kt + cg * 8), lB + rb * 512);
        }
        __syncthreads();
#pragma unroll
        for (int kk = 0; kk < 2; ++kk) {
            short8 av[4], bv[4];
#pragma unroll
            for (int m = 0; m < 4; ++m) {
                int r = wr * 64 + m * 16 + (lane & 15);
                int cc = ((kk << 2) + (lane >> 4)) ^ (r & 7);
                av[m] = *(const short8*)(lA + r * 64 + cc * 8);
            }
#pragma unroll
            for (int n = 0; n < 4; ++n) {
                int r = wc * 64 + n * 16 + (lane & 15);
                int cc = ((kk << 2) + (lane >> 4)) ^ (r & 7);
                bv[n] = *(const short8*)(lB + r * 64 + cc * 8);
            }
#pragma unroll
            for (int m = 0; m < 4; ++m)
#pragma unroll
                for (int n = 0; n < 4; ++n)
                    acc[m][n] = __builtin_amdgcn_mfma_f32_16x16x32_bf16(av[m], bv[n], acc[m][n], 0, 0, 0);
        }
        __syncthreads();
    }
#pragma unroll
    for (int m = 0; m < 4; ++m)
#pragma unroll
        for (int n = 0; n < 4; ++n) {
            int row = p0 + wr * 64 + m * 16 + ((lane >> 4) << 2);
            int col = n0 + wc * 64 + n * 16 + (lane & 15);
#pragma unroll
            for (int r = 0; r < 4; ++r) {
                float vv = acc[m][n][r];
                if constexpr (EPI == 1) vv += bf2f(addb[(size_t)(row + r) * ldOut + col]);
                outb[(size_t)(row + r) * ldOut + col] = f2bf(vv);
            }
        }
}

// ---------------- attention: per (16-pixel chunk, head) block ----------------
__global__ __launch_bounds__(256, 1) void attn_kernel(
    const u16* __restrict__ qkv, const float* __restrict__ bias, u16* __restrict__ o)
{
    __shared__ u16 qkvt[3 * 256 * 64];
    __shared__ float pl[256 * 17];
    __shared__ float bl[256];
    const int tid = threadIdx.x, lane = tid & 63, w = tid >> 6;
    const int pc = blockIdx.x, h = blockIdx.y;
    const int b = pc >> 6, hw0 = (pc & 63) << 4;
    bl[tid] = bias[h * 256 + tid];
    for (int i = 0; i < 24; ++i) {
        int idx = w * 24 + i;
        int s = idx >> 5, rb = idx & 31;
        int r = (rb << 3) + (lane >> 3);
        int cg = (lane & 7) ^ (r & 7);
        size_t grow = (size_t)b * 16384 + (size_t)(r >> 4) * 1024 + hw0 + (r & 15);
        gload16(qkv + grow * 1536 + s * 512 + h * 64 + cg * 8, qkvt + s * 16384 + rb * 512);
    }
    __syncthreads();
    {
        const int ti = tid >> 4, pix = tid & 15;
        float qv[64];
        const u16* qr = qkvt + tid * 64;
#pragma unroll
        for (int cc = 0; cc < 8; ++cc) {
            short8 qq = *(const short8*)(qr + ((cc ^ (tid & 7)) << 3));
#pragma unroll
            for (int j = 0; j < 8; ++j) qv[cc * 8 + j] = bf2f((u16)qq[j]);
        }
        float sc[16];
        for (int tj = 0; tj < 16; ++tj) {
            int rk = (tj << 4) + pix;
            const u16* kr = qkvt + 16384 + rk * 64;
            float a = 0.f;
#pragma unroll
            for (int cc = 0; cc < 8; ++cc) {
                short8 kk = *(const short8*)(kr + ((cc ^ (rk & 7)) << 3));
#pragma unroll
                for (int j = 0; j < 8; ++j) a += qv[cc * 8 + j] * bf2f((u16)kk[j]);
            }
            sc[tj] = a * 0.125f + bl[(ti << 4) + tj];
        }
        float mx = sc[0];
#pragma unroll
        for (int j = 1; j < 16; ++j) mx = fmaxf(mx, sc[j]);
        float sum = 0.f;
#pragma unroll
        for (int j = 0; j < 16; ++j) { sc[j] = __expf(sc[j] - mx); sum += sc[j]; }
        float inv = 1.f / sum;
#pragma unroll
        for (int j = 0; j < 16; ++j) pl[((pix << 4) + ti) * 17 + j] = sc[j] * inv;
    }
    __syncthreads();
    {
        const int pix = tid >> 4, dg = tid & 15;
        for (int ti = 0; ti < 16; ++ti) {
            float a0 = 0, a1 = 0, a2 = 0, a3 = 0;
            const float* pr = pl + ((pix << 4) + ti) * 17;
#pragma unroll
            for (int tj = 0; tj < 16; ++tj) {
                float pv = pr[tj];
                int rv = (tj << 4) + pix;
                const u16* vr = qkvt + 32768 + rv * 64 + (((dg >> 1) ^ (rv & 7)) << 3) + ((dg & 1) << 2);
                a0 += pv * bf2f(vr[0]); a1 += pv * bf2f(vr[1]);
                a2 += pv * bf2f(vr[2]); a3 += pv * bf2f(vr[3]);
            }
            size_t p = (size_t)b * 16384 + (size_t)ti * 1024 + hw0 + pix;
            uint2 pk;
            pk.x = (unsigned int)f2bf(a0) | ((unsigned int)f2bf(a1) << 16);
            pk.y = (unsigned int)f2bf(a2) | ((unsigned int)f2bf(a3) << 16);
            *(uint2*)(o + p * 512 + h * 64 + (dg << 2)) = pk;
        }
    }
}

// ---------------- channel-LN stats over shifted yg rows (pad cols are zeros) ----------------
__global__ __launch_bounds__(256) void stats_kernel(
    const u16* __restrict__ yg, float* __restrict__ marr, float* __restrict__ rinvv)
{
    const int lane = threadIdx.x & 63, w = threadIdx.x >> 6;
    const int gw = blockIdx.x * 4 + w;
    for (int rr = 0; rr < 16; ++rr) {
        int row = gw * 16 + rr;
        const u16* rp = yg + (size_t)row * 1408;
        float s = 0.f, q = 0.f;
        for (int it = 0; it < 3; ++it) {
            int qi = it * 64 + lane;
            if (qi < 176) {
                uint4 d = *(const uint4*)(rp + qi * 8);
#pragma unroll
                for (int e = 0; e < 4; ++e) {
                    unsigned int dd = (&d.x)[e];
                    float f0 = bf2f((u16)(dd & 0xffff)), f1 = bf2f((u16)(dd >> 16));
                    s += f0 + f1;
                    q += f0 * f0 + f1 * f1;
                }
            }
        }
        for (int off = 32; off; off >>= 1) { s += __shfl_xor(s, off); q += __shfl_xor(q, off); }
        if (lane == 0) {
            float m = s * (1.f / 1365.f);
            float var = q * (1.f / 1365.f) - m * m;
            marr[row] = m;
            rinvv[row] = rsqrtf(fmaxf(var, 1e-5f));
        }
    }
}

extern "C" void kernel_launch(void* const* d_in, const int* in_sizes, int n_in,
                              void* d_out, int out_size, void* d_ws, size_t ws_size,
                              hipStream_t stream)
{
    const float* x       = (const float*)d_in[0];
    const int*   frp     = (const int*)d_in[1];
    const float* g_norm  = (const float*)d_in[2];
    const float* Wq      = (const float*)d_in[3];
    const float* Wkv     = (const float*)d_in[4];
    const float* Wo      = (const float*)d_in[5];
    const float* pos_emb = (const float*)d_in[6];
    const float* fr_emb  = (const float*)d_in[7];
    const float* w1      = (const float*)d_in[8];
    const float* b1      = (const float*)d_in[9];
    const float* w2      = (const float*)d_in[10];
    const float* b2      = (const float*)d_in[11];
    const float* w3      = (const float*)d_in[12];
    const float* b3      = (const float*)d_in[13];
    const float* Win     = (const float*)d_in[14];
    const float* chan_g  = (const float*)d_in[15];
    const float* Wout    = (const float*)d_in[16];

    char* ws = (char*)d_ws;
    u16*   wqkvt = (u16*)(ws + 0);
    u16*   wot   = (u16*)(ws + 1572864);
    u16*   winp  = (u16*)(ws + 2097152);
    u16*   woutt = (u16*)(ws + 4980736);
    float* ssum  = (float*)(ws + 6422528);
    float* biasb = (float*)(ws + 6424576);
    float* marr  = (float*)(ws + 6432768);
    float* rinvv = (float*)(ws + 6563840);
    u16*   qkv   = (u16*)(ws + 8388608);     // reused as yg after attention
    u16*   xn    = (u16*)(ws + 109051904);   // reused as o_att after qkv GEMM
    u16*   xt    = (u16*)(ws + 142606336);
    u16*   x2    = (u16*)(ws + 176160768);
    u16*   o_att = xn;
    u16*   yg    = qkv;

    prep_weights<<<12544, 256, 0, stream>>>(Wq, Wkv, Wo, Win, Wout, chan_g, wqkvt, wot, winp, woutt);
    ssum_kernel<<<2, 256, 0, stream>>>(Wout, chan_g, ssum);
    bias_kernel<<<256, 256, 0, stream>>>(w1, b1, w2, b2, w3, b3, biasb);
    k1_norm<<<2048, 256, 0, stream>>>(x, frp, g_norm, pos_emb, fr_emb, xn, xt);
    gemm8<0><<<128 * 6, 512, 0, stream>>>(xn, wqkvt, 512, 6, qkv, nullptr, nullptr,
                                          nullptr, nullptr, nullptr, 1536);
    attn_kernel<<<dim3(128, 8), 256, 0, stream>>>(qkv, biasb, o_att);
    gemm_bt<1><<<256 * 4, 256, 0, stream>>>(o_att, wot, 512, 4, x2, nullptr, xt,
                                            nullptr, nullptr, nullptr, 512);
    gemm8<2><<<128 * 11, 512, 0, stream>>>(x2, winp, 512, 11, yg, nullptr, nullptr,
                                           nullptr, nullptr, nullptr, 1408);
    stats_kernel<<<512, 256, 0, stream>>>(yg, marr, rinvv);
    gemm8<3><<<128 * 2, 512, 0, stream>>>(yg, woutt, 1408, 2, nullptr, (float*)d_out, x2,
                                          marr, rinvv, ssum, 512);
}

// Round 5
// 437.630 us; speedup vs baseline: 1.4316x; 1.4316x over previous
//
#include <hip/hip_runtime.h>

using u16 = unsigned short;
using f32x4 = __attribute__((ext_vector_type(4))) float;
using short8 = __attribute__((ext_vector_type(8))) short;

__device__ __forceinline__ float bf2f(u16 u) {
    union { unsigned int i; float f; } v; v.i = ((unsigned int)u) << 16; return v.f;
}
__device__ __forceinline__ u16 f2bf(float f) {
    union { float f; unsigned int i; } v; v.f = f;
    unsigned int u = v.i;
    u += 0x7fffu + ((u >> 16) & 1u);
    return (u16)(u >> 16);
}
__device__ __forceinline__ void gload16(const u16* g, u16* l) {
    __builtin_amdgcn_global_load_lds((const __attribute__((address_space(1))) void*)g,
                                     (__attribute__((address_space(3))) void*)l, 16, 0, 0);
}

// ---------------- prep: weight transposes/permutations to bf16 ----------------
// wqkvt [1536][512]: n<512 -> Wq[c][n]; else Wkv[c][n-512]
// wot   [512][512]:  Wo^T
// winp  [2816][512]: col-permuted Win^T: block of 32 rows = 16 val rows then 16 gate rows
// woutt [512][1408]: Wout^T * chan_g, K padded 1365->1408 with zeros
__global__ __launch_bounds__(256) void prep_weights(
    const float* __restrict__ Wq, const float* __restrict__ Wkv,
    const float* __restrict__ Wo, const float* __restrict__ Win,
    const float* __restrict__ Wout, const float* __restrict__ cg,
    u16* __restrict__ wqkvt, u16* __restrict__ wot,
    u16* __restrict__ winp, u16* __restrict__ woutt)
{
    int i = blockIdx.x * 256 + threadIdx.x;
    if (i < 1536 * 512) {
        int n = i >> 9, c = i & 511;
        float v = (n < 512) ? Wq[c * 512 + n] : Wkv[c * 1024 + (n - 512)];
        wqkvt[i] = f2bf(v); return;
    }
    i -= 1536 * 512;
    if (i < 512 * 512) {
        int cc = i >> 9, k = i & 511;
        wot[i] = f2bf(Wo[k * 512 + cc]); return;
    }
    i -= 512 * 512;
    if (i < 2816 * 512) {
        int n = i >> 9, c = i & 511;
        int jj = ((n >> 5) << 4) + (n & 15);
        int gate = (n >> 4) & 1;
        float v = (jj < 1365) ? Win[c * 2730 + jj + gate * 1365] : 0.f;
        winp[i] = f2bf(v); return;
    }
    i -= 2816 * 512;
    if (i < 512 * 1408) {
        int cc = i / 1408, j = i % 1408;
        float v = (j < 1365) ? Wout[j * 512 + cc] * cg[j] : 0.f;
        woutt[i] = f2bf(v); return;
    }
}

// ssum[c] = sum_j Wout[j][c]*cg[j]; 512 blocks x 64 threads (parallel, was 2-block serial)
__global__ __launch_bounds__(64) void ssum_kernel(
    const float* __restrict__ Wout, const float* __restrict__ cg, float* __restrict__ ssum)
{
    int c = blockIdx.x;
    int lane = threadIdx.x;
    float s = 0.f;
    for (int j = lane; j < 1365; j += 64) s += Wout[j * 512 + c] * cg[j];
    for (int off = 32; off; off >>= 1) s += __shfl_xor(s, off);
    if (lane == 0) ssum[c] = s;
}

// ---------------- CPB relative-position bias MLP: bias[8][16][16] ----------------
__global__ __launch_bounds__(256) void bias_kernel(
    const float* __restrict__ w1, const float* __restrict__ b1,
    const float* __restrict__ w2, const float* __restrict__ b2,
    const float* __restrict__ w3, const float* __restrict__ b3,
    float* __restrict__ bias)
{
    __shared__ float h1[256], h2[256];
    int rc = blockIdx.x;
    int ti = rc >> 4, tj = rc & 15;
    int j = threadIdx.x;
    float r = (float)(ti - tj);
    float rl = (r > 0.f) ? logf(r + 1.f) : ((r < 0.f) ? -logf(1.f - r) : 0.f);
    float a = rl * w1[j] + b1[j];
    h1[j] = a / (1.f + __expf(-a));
    __syncthreads();
    float acc = b2[j];
    for (int k = 0; k < 256; ++k) acc += h1[k] * w2[k * 256 + j];
    h2[j] = acc / (1.f + __expf(-acc));
    __syncthreads();
    if (j < 8) {
        float ab = b3[j];
        for (int k = 0; k < 256; ++k) ab += h2[k] * w3[k * 8 + j];
        bias[j * 256 + ti * 16 + tj] = ab;
    }
}

// ---------------- K1: temporal LayerNorm, write xn & xt token-major bf16 ----------------
__global__ __launch_bounds__(256) void k1_norm(
    const float* __restrict__ x, const int* __restrict__ frp,
    const float* __restrict__ g_norm, const float* __restrict__ pos_emb,
    const float* __restrict__ fr_emb,
    u16* __restrict__ xn, u16* __restrict__ xt)
{
    __shared__ u16 tile[256 * 34];
    const int bid = blockIdx.x;
    const int b = bid >> 10, rem = bid & 1023;
    const int hw0 = (rem >> 4) << 4;
    const int c0 = (rem & 15) << 5;
    const int tid = threadIdx.x;
    const int hwl = tid & 15, cl = tid >> 4;
    const int fr = frp[0] - 1;
    float v[2][16], mean2[2], ri2[2], gg2[2], fv2[2];
    for (int cp = 0; cp < 2; ++cp) {
        const int c = c0 + cl + (cp << 4);
        const float* xp = x + (size_t)(b * 512 + c) * 16384 + hw0 + hwl;
        const float fv = fr_emb[fr * 512 + c];
        float s1 = 0.f, s2 = 0.f;
#pragma unroll
        for (int t = 0; t < 16; ++t) {
            float xv = xp[t * 1024];
            v[cp][t] = xv;
            float xe = xv + pos_emb[t * 512 + c] + fv;
            s1 += xe; s2 += xe * xe;
        }
        float m = s1 * 0.0625f;
        float var = s2 * 0.0625f - m * m;
        mean2[cp] = m; ri2[cp] = rsqrtf(fmaxf(var, 1e-5f));
        gg2[cp] = g_norm[c]; fv2[cp] = fv;
    }
    for (int cp = 0; cp < 2; ++cp) {
        const int c = c0 + cl + (cp << 4);
#pragma unroll
        for (int t = 0; t < 16; ++t) {
            float xe = v[cp][t] + pos_emb[t * 512 + c] + fv2[cp];
            tile[((t << 4) + hwl) * 34 + cl + (cp << 4)] = f2bf((xe - mean2[cp]) * ri2[cp] * gg2[cp]);
        }
    }
    __syncthreads();
    for (int it = 0; it < 32; ++it) {
        int rowl = (tid >> 5) + (it << 3);
        int col = tid & 31;
        size_t p = (size_t)b * 16384 + (size_t)(rowl >> 4) * 1024 + hw0 + (rowl & 15);
        xn[p * 512 + c0 + col] = tile[rowl * 34 + col];
    }
    __syncthreads();
    for (int cp = 0; cp < 2; ++cp)
#pragma unroll
        for (int t = 0; t < 16; ++t)
            tile[((t << 4) + hwl) * 34 + cl + (cp << 4)] = f2bf(v[cp][t]);
    __syncthreads();
    for (int it = 0; it < 32; ++it) {
        int rowl = (tid >> 5) + (it << 3);
        int col = tid & 31;
        size_t p = (size_t)b * 16384 + (size_t)(rowl >> 4) * 1024 + hw0 + (rowl & 15);
        xt[p * 512 + c0 + col] = tile[rowl * 34 + col];
    }
}

// ---------------- generic MFMA GEMM: C[M=32768][N] = A[M][K] * B^T[N][K] ----------------
// 128x128 tile, 256 thr, single-buffer 2-barrier (proven structure) + XCD-chunked swizzle.
// EPI 3 additionally computes per-row channel-LN stats INLINE from the av fragments
// (wc==0 waves, zero extra LDS traffic) — replaces the separate stats kernel.
template<int EPI>
__global__ __launch_bounds__(256, 2) void gemm_bt(
    const u16* __restrict__ A, const u16* __restrict__ B, int K, int Nb,
    u16* __restrict__ outb, float* __restrict__ outf,
    const u16* __restrict__ addb,
    const float* __restrict__ ssum, int ldOut)
{
    __shared__ u16 lds[2 * 128 * 64];
    __shared__ float smr[256];          // EPI3: [0:128) mean, [128:256) rinv
    u16* lA = lds;
    u16* lB = lds + 128 * 64;
    const int tid = threadIdx.x, lane = tid & 63, w = tid >> 6;
    const int wr = w >> 1, wc = w & 1;
    const int cpx = gridDim.x >> 3;
    const int wgid = (blockIdx.x & 7) * cpx + (blockIdx.x >> 3);
    const int p0 = (wgid / Nb) * 128, n0 = (wgid % Nb) * 128;
    f32x4 acc[4][4] = {};
    float sst[4] = {}, sq[4] = {};
    for (int kt = 0; kt < K; kt += 64) {
        for (int i = 0; i < 4; ++i) {
            int rb = w * 4 + i;
            int r = rb * 8 + (lane >> 3);
            int cg = (lane & 7) ^ (r & 7);
            gload16(A + (size_t)(p0 + r) * K + (kt + cg * 8), lA + rb * 512);
            gload16(B + (size_t)(n0 + r) * K + (kt + cg * 8), lB + rb * 512);
        }
        __syncthreads();
#pragma unroll
        for (int kk = 0; kk < 2; ++kk) {
            short8 av[4], bv[4];
#pragma unroll
            for (int m = 0; m < 4; ++m) {
                int r = wr * 64 + m * 16 + (lane & 15);
                int cc = ((kk << 2) + (lane >> 4)) ^ (r & 7);
                av[m] = *(const short8*)(lA + r * 64 + cc * 8);
            }
#pragma unroll
            for (int n = 0; n < 4; ++n) {
                int r = wc * 64 + n * 16 + (lane & 15);
                int cc = ((kk << 2) + (lane >> 4)) ^ (r & 7);
                bv[n] = *(const short8*)(lB + r * 64 + cc * 8);
            }
            if constexpr (EPI == 3) {
                if (wc == 0) {
#pragma unroll
                    for (int m = 0; m < 4; ++m)
#pragma unroll
                        for (int j = 0; j < 8; ++j) {
                            float v = bf2f((u16)av[m][j]);
                            sst[m] += v; sq[m] += v * v;
                        }
                }
            }
#pragma unroll
            for (int m = 0; m < 4; ++m)
#pragma unroll
                for (int n = 0; n < 4; ++n)
                    acc[m][n] = __builtin_amdgcn_mfma_f32_16x16x32_bf16(av[m], bv[n], acc[m][n], 0, 0, 0);
        }
        __syncthreads();
    }

    if constexpr (EPI == 0 || EPI == 1) {
#pragma unroll
        for (int m = 0; m < 4; ++m)
#pragma unroll
            for (int n = 0; n < 4; ++n) {
                int row = p0 + wr * 64 + m * 16 + ((lane >> 4) << 2);
                int col = n0 + wc * 64 + n * 16 + (lane & 15);
#pragma unroll
                for (int r = 0; r < 4; ++r) {
                    float vv = acc[m][n][r];
                    if constexpr (EPI == 1) vv += bf2f(addb[(size_t)(row + r) * ldOut + col]);
                    outb[(size_t)(row + r) * ldOut + col] = f2bf(vv);
                }
            }
    } else if constexpr (EPI == 2) {
#pragma unroll
        for (int m = 0; m < 4; ++m)
#pragma unroll
            for (int np = 0; np < 2; ++np) {
                int nv = np << 1;
                int colBase = n0 + wc * 64 + nv * 16 + (lane & 15);
                int jj = ((colBase >> 5) << 4) + (colBase & 15);
                int rowb = p0 + wr * 64 + m * 16 + ((lane >> 4) << 2);
                int t = (rowb >> 10) & 15;
#pragma unroll
                for (int r = 0; r < 4; ++r) {
                    int p = rowb + r;
                    float vv = acc[m][nv][r], gv = acc[m][nv + 1][r];
                    float glu = vv * 0.5f * gv * (1.f + erff(gv * 0.70710678f));
                    if (jj >= 1365) {
                        outb[(size_t)p * 1408 + jj] = 0;
                    } else if (jj >= 683) {
                        if (t < 15) outb[(size_t)(p + 1024) * 1408 + jj] = f2bf(glu);
                        if (t == 0) outb[(size_t)p * 1408 + jj] = 0;
                    } else {
                        outb[(size_t)p * 1408 + jj] = f2bf(glu);
                    }
                }
            }
    } else {
        // EPI 3: finish inline stats, then channel-LN apply + residual + transposed fp32 store
        if (wc == 0) {
#pragma unroll
            for (int m = 0; m < 4; ++m) {
                float s = sst[m], q = sq[m];
                s += __shfl_xor(s, 16); q += __shfl_xor(q, 16);
                s += __shfl_xor(s, 32); q += __shfl_xor(q, 32);
                if ((lane >> 4) == 0) {
                    int row = wr * 64 + m * 16 + (lane & 15);
                    smr[row] = s; smr[128 + row] = q;
                }
            }
        }
        __syncthreads();
        if (tid < 128) {
            float mm = smr[tid] * (1.f / 1365.f);
            float var = smr[128 + tid] * (1.f / 1365.f) - mm * mm;
            smr[tid] = mm;
            smr[128 + tid] = rsqrtf(fmaxf(var, 1e-5f));
        }
        float* ldsT = (float*)lds;
        const int bb = p0 >> 14, tt = (p0 >> 10) & 15, hwb = p0 & 1023;
        float* outp = outf + (size_t)bb * 8388608 + (size_t)tt * 1024 + hwb;
        for (int cg4 = 0; cg4 < 4; ++cg4) {
            __syncthreads();
            if (wc == (cg4 >> 1)) {
#pragma unroll
                for (int m = 0; m < 4; ++m)
#pragma unroll
                    for (int nn = 0; nn < 2; ++nn) {
                        int n = ((cg4 & 1) << 1) + nn;
                        int cl2 = (nn << 4) + (lane & 15);
                        int col = n0 + wc * 64 + n * 16 + (lane & 15);
                        int rl = wr * 64 + m * 16 + ((lane >> 4) << 2);
                        float ssv = ssum[col];
#pragma unroll
                        for (int r = 0; r < 4; ++r) {
                            int p = p0 + rl + r;
                            float vv = smr[128 + rl + r] * (acc[m][n][r] - smr[rl + r] * ssv)
                                     + bf2f(addb[(size_t)p * 512 + col]);
                            ldsT[cl2 * 132 + rl + r] = vv;
                        }
                    }
            }
            __syncthreads();
#pragma unroll
            for (int e = 0; e < 16; ++e) {
                int li = e * 256 + tid;
                int cl2 = li >> 7, hwl = li & 127;
                outp[(size_t)(n0 + cg4 * 32 + cl2) * 16384 + hwl] = ldsT[cl2 * 132 + hwl];
            }
        }
    }
}

// ---------------- attention: per (8-pixel chunk, head) block; 2 blocks/CU ----------------
__global__ __launch_bounds__(256, 2) void attn_kernel(
    const u16* __restrict__ qkv, const float* __restrict__ bias, u16* __restrict__ o)
{
    __shared__ u16 qkvt[3 * 128 * 64];     // 48 KB: rows r = t*8 + pix
    __shared__ float pl[128 * 17];         // 8.5 KB score/prob rows
    __shared__ float bl[256];
    const int tid = threadIdx.x, lane = tid & 63, w = tid >> 6;
    const int pc = blockIdx.x, h = blockIdx.y;
    const int b = pc >> 7, hw0 = (pc & 127) << 3;
    bl[tid] = bias[h * 256 + tid];
    for (int i = 0; i < 12; ++i) {
        int idx = w * 12 + i;              // 48 row-blocks of 8 rows (16 per s)
        int s = idx >> 4, rb = idx & 15;
        int r = (rb << 3) + (lane >> 3);
        int cg = (lane & 7) ^ (r & 7);
        size_t grow = (size_t)b * 16384 + (size_t)(r >> 3) * 1024 + hw0 + (r & 7);
        gload16(qkv + grow * 1536 + s * 512 + h * 64 + cg * 8, qkvt + s * 8192 + rb * 512);
    }
    __syncthreads();
    {
        // QK^T: thread = (qrow 0..127, half hh): 8 tj each
        const int qrow = tid & 127, hh = tid >> 7;
        const int pix = qrow & 7, ti = qrow >> 3;
        float qv[64];
        const u16* qr = qkvt + qrow * 64;
#pragma unroll
        for (int cc = 0; cc < 8; ++cc) {
            short8 qq = *(const short8*)(qr + ((cc ^ (qrow & 7)) << 3));
#pragma unroll
            for (int j = 0; j < 8; ++j) qv[cc * 8 + j] = bf2f((u16)qq[j]);
        }
#pragma unroll
        for (int tj8 = 0; tj8 < 8; ++tj8) {
            int tj = (hh << 3) + tj8;
            int rk = (tj << 3) + pix;
            const u16* kr = qkvt + 8192 + rk * 64;
            float a = 0.f;
#pragma unroll
            for (int cc = 0; cc < 8; ++cc) {
                short8 kk = *(const short8*)(kr + ((cc ^ (rk & 7)) << 3));
#pragma unroll
                for (int j = 0; j < 8; ++j) a += qv[cc * 8 + j] * bf2f((u16)kk[j]);
            }
            pl[qrow * 17 + tj] = a * 0.125f + bl[(ti << 4) + tj];
        }
    }
    __syncthreads();
    if (tid < 128) {
        float sc[16];
#pragma unroll
        for (int j = 0; j < 16; ++j) sc[j] = pl[tid * 17 + j];
        float mx = sc[0];
#pragma unroll
        for (int j = 1; j < 16; ++j) mx = fmaxf(mx, sc[j]);
        float sum = 0.f;
#pragma unroll
        for (int j = 0; j < 16; ++j) { sc[j] = __expf(sc[j] - mx); sum += sc[j]; }
        float inv = 1.f / sum;
#pragma unroll
        for (int j = 0; j < 16; ++j) pl[tid * 17 + j] = sc[j] * inv;
    }
    __syncthreads();
    {
        // PV: thread = (pix 0..7, dg 0..31) -> 2 channels; V hoisted to regs (16x reuse)
        const int pix = tid >> 5, dg = tid & 31;
        float v0[16], v1[16];
#pragma unroll
        for (int tj = 0; tj < 16; ++tj) {
            int rv = (tj << 3) + pix;
            unsigned int d = *(const unsigned int*)(qkvt + 16384 + rv * 64 +
                               (((dg >> 2) ^ (rv & 7)) << 3) + ((dg & 3) << 1));
            v0[tj] = bf2f((u16)(d & 0xffff));
            v1[tj] = bf2f((u16)(d >> 16));
        }
#pragma unroll
        for (int ti = 0; ti < 16; ++ti) {
            float a0 = 0.f, a1 = 0.f;
            const float* pr = pl + ((ti << 3) + pix) * 17;
#pragma unroll
            for (int tj = 0; tj < 16; ++tj) {
                float pv = pr[tj];
                a0 += pv * v0[tj];
                a1 += pv * v1[tj];
            }
            size_t p = (size_t)b * 16384 + (size_t)ti * 1024 + hw0 + pix;
            unsigned int pk = (unsigned int)f2bf(a0) | ((unsigned int)f2bf(a1) << 16);
            *(unsigned int*)(o + p * 512 + h * 64 + (dg << 1)) = pk;
        }
    }
}

extern "C" void kernel_launch(void* const* d_in, const int* in_sizes, int n_in,
                              void* d_out, int out_size, void* d_ws, size_t ws_size,
                              hipStream_t stream)
{
    const float* x       = (const float*)d_in[0];
    const int*   frp     = (const int*)d_in[1];
    const float* g_norm  = (const float*)d_in[2];
    const float* Wq      = (const float*)d_in[3];
    const float* Wkv     = (const float*)d_in[4];
    const float* Wo      = (const float*)d_in[5];
    const float* pos_emb = (const float*)d_in[6];
    const float* fr_emb  = (const float*)d_in[7];
    const float* w1      = (const float*)d_in[8];
    const float* b1      = (const float*)d_in[9];
    const float* w2      = (const float*)d_in[10];
    const float* b2      = (const float*)d_in[11];
    const float* w3      = (const float*)d_in[12];
    const float* b3      = (const float*)d_in[13];
    const float* Win     = (const float*)d_in[14];
    const float* chan_g  = (const float*)d_in[15];
    const float* Wout    = (const float*)d_in[16];

    char* ws = (char*)d_ws;
    u16*   wqkvt = (u16*)(ws + 0);
    u16*   wot   = (u16*)(ws + 1572864);
    u16*   winp  = (u16*)(ws + 2097152);
    u16*   woutt = (u16*)(ws + 4980736);
    float* ssum  = (float*)(ws + 6422528);
    float* biasb = (float*)(ws + 6424576);
    u16*   qkv   = (u16*)(ws + 8388608);     // reused as yg after attention
    u16*   xn    = (u16*)(ws + 109051904);   // reused as o_att after qkv GEMM
    u16*   xt    = (u16*)(ws + 142606336);
    u16*   x2    = (u16*)(ws + 176160768);
    u16*   o_att = xn;
    u16*   yg    = qkv;

    prep_weights<<<12544, 256, 0, stream>>>(Wq, Wkv, Wo, Win, Wout, chan_g, wqkvt, wot, winp, woutt);
    ssum_kernel<<<512, 64, 0, stream>>>(Wout, chan_g, ssum);
    bias_kernel<<<256, 256, 0, stream>>>(w1, b1, w2, b2, w3, b3, biasb);
    k1_norm<<<2048, 256, 0, stream>>>(x, frp, g_norm, pos_emb, fr_emb, xn, xt);
    gemm_bt<0><<<256 * 12, 256, 0, stream>>>(xn, wqkvt, 512, 12, qkv, nullptr, nullptr,
                                             nullptr, 1536);
    attn_kernel<<<dim3(256, 8), 256, 0, stream>>>(qkv, biasb, o_att);
    gemm_bt<1><<<256 * 4, 256, 0, stream>>>(o_att, wot, 512, 4, x2, nullptr, xt,
                                            nullptr, 512);
    gemm_bt<2><<<256 * 22, 256, 0, stream>>>(x2, winp, 512, 22, yg, nullptr, nullptr,
                                             nullptr, 1408);
    gemm_bt<3><<<256 * 4, 256, 0, stream>>>(yg, woutt, 1408, 4, nullptr, (float*)d_out, x2,
                                            ssum, 512);
}